// Round 4
// baseline (254.452 us; speedup 1.0000x reference)
//
#include <hip/hip_runtime.h>

#define NPIX 4096
#define SCALE 0.125f

typedef _Float16 half8 __attribute__((ext_vector_type(8)));
typedef _Float16 half4 __attribute__((ext_vector_type(4)));
typedef float floatx4 __attribute__((ext_vector_type(4)));

// async global->LDS, 16B per lane. lds base must be wave-uniform; data lands
// at base + lane*16 (gfx950 semantics, learn_hip m97/m104).
__device__ __forceinline__ void async16(void* lds, const void* g) {
  __builtin_amdgcn_global_load_lds(
      (const __attribute__((address_space(1))) unsigned int*)(uintptr_t)g,
      (__attribute__((address_space(3))) unsigned int*)(unsigned)(uintptr_t)lds,
      16, 0, 0);
}

// ---------------------------------------------------------------------------
// split fp32 -> hi/lo fp16 (a = hi + lo, ~21 mantissa bits kept)
// ---------------------------------------------------------------------------
__global__ __launch_bounds__(256) void split16_kernel(const float* __restrict__ w,
                                                      _Float16* __restrict__ hi,
                                                      _Float16* __restrict__ lo, int n) {
  int i = blockIdx.x * 256 + threadIdx.x;
  if (i < n) {
    float v = w[i];
    _Float16 h = (_Float16)v;
    hi[i] = h;
    lo[i] = (_Float16)(v - (float)h);
  }
}

// ---------------------------------------------------------------------------
// x[b][256][4096] fp32 -> xt[b][4096][256] fp16 (K-contiguous for B-operand)
// ---------------------------------------------------------------------------
__global__ __launch_bounds__(256) void transpose16_kernel(const float* __restrict__ x,
                                                          _Float16* __restrict__ xt) {
  __shared__ float t[64][65];
  const int n0 = blockIdx.x * 64, c0 = blockIdx.y * 64, b = blockIdx.z;
  const float* xp = x + (long)b * 256 * NPIX;
  const int tid = threadIdx.x;
  const int r = tid >> 4, c4 = (tid & 15) * 4;
#pragma unroll
  for (int p = 0; p < 4; p++) {
    float4 v = *(const float4*)&xp[(long)(c0 + r + p * 16) * NPIX + n0 + c4];
    t[r + p * 16][c4 + 0] = v.x;
    t[r + p * 16][c4 + 1] = v.y;
    t[r + p * 16][c4 + 2] = v.z;
    t[r + p * 16][c4 + 3] = v.w;
  }
  __syncthreads();
  const int n = tid >> 2, cg = (tid & 3) * 16;
  alignas(16) _Float16 o[16];
#pragma unroll
  for (int i = 0; i < 16; i++) o[i] = (_Float16)t[cg + i][n];
  _Float16* dst = &xt[((long)b * NPIX + n0 + n) * 256 + c0 + cg];
  *(float4*)dst = *(float4*)&o[0];
  *(float4*)(dst + 8) = *(float4*)&o[8];
}

// ===========================================================================
// 512-thread GEMM tile: BM=128, BN=256, BK=32, 8 waves (2M x 4N of 64x64).
// Staging per buffer: Ah 8KB | Al 8KB | B 16KB = 32KB; dbuf = 64KB ->
// 2 blocks/CU x 8 waves = 16 waves/CU (50% occ). VGPR pinned to 128.
// ===========================================================================

// ---------------------------------------------------------------------------
// FUSED q-GEMM + column softmax over d. 2-phase prefetch double-buffer.
// ---------------------------------------------------------------------------
__global__ __launch_bounds__(512, 4) void q_gemm_softmax(const _Float16* __restrict__ Ahp,
                                                         const _Float16* __restrict__ Alp,
                                                         const _Float16* __restrict__ Bt,
                                                         _Float16* __restrict__ PT) {
  union alignas(16) QU {
    _Float16 st[2][16384];   // [buf]: Ah[0,4096) Al[4096,8192) B[8192,16384)
    _Float16 pt[256][128];   // 64 KB epilogue P-tile (XOR-swizzled cols)
  };
  __shared__ QU u;
  const int tid = threadIdx.x;
  const int n0 = blockIdx.x * 256, m0 = blockIdx.y * 128;
  const int bz = blockIdx.z;
  const _Float16* Bp = Bt + (long)bz * NPIX * 256;
  const int wv = tid >> 6, l = tid & 63;
  const int r16 = l & 15, q = l >> 4;
  const int mb = (wv >> 2) * 64, nb = (wv & 3) * 64;
  const int r1 = tid >> 2;  // 0..127
  const int o1 = ((tid & 3) * 8) ^ (((r1 >> 1) & 3) * 8);
  const int ldsA = wv * 512;  // halves; each wave stages 1KB per call
  const int q8 = (q * 8) ^ (((r16 >> 1) & 3) * 8);

  auto STAGE = [&](int buf, int kt) {
    const int k0 = kt * 32;
    _Float16* base = u.st[buf];
    async16(&base[ldsA], &Ahp[(long)(m0 + r1) * 256 + k0 + o1]);
    async16(&base[4096 + ldsA], &Alp[(long)(m0 + r1) * 256 + k0 + o1]);
    async16(&base[8192 + ldsA], &Bp[(long)(n0 + r1) * 256 + k0 + o1]);
    async16(&base[12288 + ldsA], &Bp[(long)(n0 + 128 + r1) * 256 + k0 + o1]);
  };

  floatx4 acc[4][4];
#pragma unroll
  for (int i = 0; i < 4; i++)
#pragma unroll
    for (int j = 0; j < 4; j++) acc[i][j] = (floatx4){0.f, 0.f, 0.f, 0.f};

  STAGE(0, 0);
  __syncthreads();
  int cur = 0;
  for (int kt = 0; kt < 8; kt++) {
    if (kt < 7) STAGE(cur ^ 1, kt + 1);
    half8 fa[4], flo[4], fb[4];
#pragma unroll
    for (int i = 0; i < 4; i++) {
      fa[i] = *(const half8*)&u.st[cur][(mb + i * 16 + r16) * 32 + q8];
      flo[i] = *(const half8*)&u.st[cur][4096 + (mb + i * 16 + r16) * 32 + q8];
      fb[i] = *(const half8*)&u.st[cur][8192 + (nb + i * 16 + r16) * 32 + q8];
    }
#pragma unroll
    for (int i = 0; i < 4; i++)
#pragma unroll
      for (int j = 0; j < 4; j++) {
        acc[i][j] = __builtin_amdgcn_mfma_f32_16x16x32_f16(fa[i], fb[j], acc[i][j], 0, 0, 0);
        acc[i][j] = __builtin_amdgcn_mfma_f32_16x16x32_f16(flo[i], fb[j], acc[i][j], 0, 0, 0);
      }
    __syncthreads();
    cur ^= 1;
  }

  // ---- epilogue: per-column softmax over d (each wave = one full head) ----
#pragma unroll
  for (int j = 0; j < 4; j++) {
    float s = 0.f;
#pragma unroll
    for (int i = 0; i < 4; i++)
#pragma unroll
      for (int t = 0; t < 4; t++) {
        float e = __expf(acc[i][j][t]);
        acc[i][j][t] = e;
        s += e;
      }
    s += __shfl_xor(s, 16, 64);
    s += __shfl_xor(s, 32, 64);
    const float rinv = 1.0f / s;
    const int nl = nb + j * 16 + r16;  // 0..255
    const int swz = (nl & 7) * 8;
#pragma unroll
    for (int i = 0; i < 4; i++) {
      half4 h4;
#pragma unroll
      for (int t = 0; t < 4; t++) h4[t] = (_Float16)(acc[i][j][t] * rinv);
      *(half4*)&u.pt[nl][(mb + i * 16 + q * 4) ^ swz] = h4;
    }
  }
  __syncthreads();
  // ---- dump P-tile (256 n x 128 c): rows contiguous in PT ----
  const int rbase = tid >> 4, c16 = tid & 15;
  _Float16* dst = PT + ((long)(bz * 2 + (m0 >> 7)) * NPIX + n0) * 128;
#pragma unroll
  for (int k = 0; k < 8; k++) {
    const int row = rbase + k * 32;
    const int chunk = c16 ^ (row & 7);
    float4 v = *(const float4*)&u.pt[row][chunk * 8];
    *(float4*)&dst[(long)row * 128 + c16 * 8] = v;
  }
}

// ---------------------------------------------------------------------------
// FUSED k/v GEMM + exp(k)@v^T context partials. BN=256 chunks, CPB=2 chunks
// per block (c2 accumulates in MFMA C-regs across chunks). Context step:
// wave (h2 = wv>>2) takes n-half, (dblk = wv&3) takes d-block -> 16 partials
// per bh (8 cg x 2 halves).
// ---------------------------------------------------------------------------
#define CPB 2
__global__ __launch_bounds__(512, 4) void kv_ctx_gemm(const _Float16* __restrict__ Ahp,
                                                      const _Float16* __restrict__ Alp,
                                                      const _Float16* __restrict__ Bt,
                                                      float* __restrict__ pbuf,
                                                      float* __restrict__ rsbuf) {
  union alignas(16) KVU {
    _Float16 st[2][16384];  // 64 KB dbuf staging
    _Float16 ev[128][264];  // 66 KB epilogue: rows 0..63 exp(k), 64..127 v
  };
  __shared__ KVU u;
  const int tid = threadIdx.x;
  const int cg = blockIdx.x;  // 0..7 chunk-group (2 chunks of 256 n each)
  const int hi = blockIdx.y;  // head 0..3
  const int b = blockIdx.z;
  const _Float16* Bp = Bt + (long)b * NPIX * 256;
  const int wv = tid >> 6, l = tid & 63;
  const int r16 = l & 15, q = l >> 4;
  const int mb = (wv >> 2) * 64, nb = (wv & 3) * 64;
  const int r1 = tid >> 2;  // 0..127
  const int o1 = ((tid & 3) * 8) ^ (((r1 >> 1) & 3) * 8);
  const int ldsA = wv * 512;
  const int q8 = (q * 8) ^ (((r16 >> 1) & 3) * 8);
  // A rows: local 0..63 = k[head hi], 64..127 = v[head hi]
  const long gA = (long)((r1 < 64 ? 256 : 448) + hi * 64 + r1) * 256;

  auto STAGE = [&](int buf, int kt, int n0) {
    const int k0 = kt * 32;
    _Float16* base = u.st[buf];
    async16(&base[ldsA], &Ahp[gA + k0 + o1]);
    async16(&base[4096 + ldsA], &Alp[gA + k0 + o1]);
    async16(&base[8192 + ldsA], &Bp[(long)(n0 + r1) * 256 + k0 + o1]);
    async16(&base[12288 + ldsA], &Bp[(long)(n0 + 128 + r1) * 256 + k0 + o1]);
  };

  floatx4 c2[4];
#pragma unroll
  for (int j = 0; j < 4; j++) c2[j] = (floatx4){0.f, 0.f, 0.f, 0.f};
  float rs = 0.f;
  const int h2 = wv >> 2, dblk = wv & 3;  // context-step wave roles

  for (int cs = 0; cs < CPB; cs++) {
    const int n0 = (cg * CPB + cs) * 256;
    floatx4 acc[4][4];
#pragma unroll
    for (int i = 0; i < 4; i++)
#pragma unroll
      for (int j = 0; j < 4; j++) acc[i][j] = (floatx4){0.f, 0.f, 0.f, 0.f};

    STAGE(0, 0, n0);
    __syncthreads();
    int cur = 0;
    for (int kt = 0; kt < 8; kt++) {
      if (kt < 7) STAGE(cur ^ 1, kt + 1, n0);
      half8 fa[4], flo[4], fb[4];
#pragma unroll
      for (int i = 0; i < 4; i++) {
        fa[i] = *(const half8*)&u.st[cur][(mb + i * 16 + r16) * 32 + q8];
        flo[i] = *(const half8*)&u.st[cur][4096 + (mb + i * 16 + r16) * 32 + q8];
        fb[i] = *(const half8*)&u.st[cur][8192 + (nb + i * 16 + r16) * 32 + q8];
      }
#pragma unroll
      for (int i = 0; i < 4; i++)
#pragma unroll
        for (int j = 0; j < 4; j++) {
          acc[i][j] = __builtin_amdgcn_mfma_f32_16x16x32_f16(fa[i], fb[j], acc[i][j], 0, 0, 0);
          acc[i][j] = __builtin_amdgcn_mfma_f32_16x16x32_f16(flo[i], fb[j], acc[i][j], 0, 0, 0);
        }
      __syncthreads();
      cur ^= 1;
    }

    // ---- epilogue: acc -> exp(k)/v fp16 tile in LDS (stride 264) ----
    const bool is_k = (mb == 0);
#pragma unroll
    for (int i = 0; i < 4; i++) {
      const int row = mb + i * 16 + q * 4;
#pragma unroll
      for (int j = 0; j < 4; j++) {
        const int col = nb + j * 16 + r16;
#pragma unroll
        for (int t = 0; t < 4; t++) {
          const float vv0 = acc[i][j][t];
          u.ev[row + t][col] = (_Float16)(is_k ? __expf(vv0) : vv0);
        }
      }
    }
    __syncthreads();

    // ---- context partial: c2[d][e] += sum_{n in half h2} exp(k) * v ----
#pragma unroll
    for (int ks = 0; ks < 4; ks++) {
      half8 a = *(const half8*)&u.ev[dblk * 16 + r16][h2 * 128 + ks * 32 + q * 8];
#pragma unroll
      for (int ii = 0; ii < 8; ii++) rs += (float)a[ii];
#pragma unroll
      for (int j = 0; j < 4; j++) {
        half8 bv = *(const half8*)&u.ev[64 + j * 16 + r16][h2 * 128 + ks * 32 + q * 8];
        c2[j] = __builtin_amdgcn_mfma_f32_16x16x32_f16(a, bv, c2[j], 0, 0, 0);
      }
    }
    __syncthreads();  // ev reads done before next chunk's STAGE overwrites
  }

  rs += __shfl_xor(rs, 16, 64);
  rs += __shfl_xor(rs, 32, 64);
  const int bh = b * 4 + hi;
  const int part = cg * 2 + h2;  // 0..15
  float* pp = pbuf + ((long)bh * 16 + part) * 4096;
#pragma unroll
  for (int j = 0; j < 4; j++)
#pragma unroll
    for (int reg = 0; reg < 4; reg++)
      pp[(dblk * 16 + q * 4 + reg) * 64 + j * 16 + r16] = c2[j][reg];
  if (l < 16) rsbuf[((long)bh * 16 + part) * 64 + dblk * 16 + r16] = rs;
}

// ---------------------------------------------------------------------------
// ctx[bh][4096] = sum over 16 partials (deterministic, no atomics)
// ---------------------------------------------------------------------------
__global__ __launch_bounds__(256) void reduce_ctx(const float* __restrict__ pbuf,
                                                  float* __restrict__ ctx) {
  int g = blockIdx.x * 256 + threadIdx.x;  // 0..262143
  int bh = g >> 12, e = g & 4095;
  const float* pp = pbuf + ((long)bh * 16) * 4096 + e;
  float s = 0.f;
#pragma unroll
  for (int c = 0; c < 16; c++) s += pp[(long)c * 4096];
  ctx[g] = s;
}

// ---------------------------------------------------------------------------
// kinvz[bh*64+d] = 1 / sum over 16 partial row-sums
// ---------------------------------------------------------------------------
__global__ __launch_bounds__(256) void zinv_kernel(const float* __restrict__ rsbuf,
                                                   float* __restrict__ kinvz) {
  int g = blockIdx.x * 256 + threadIdx.x;  // 0..4095 = bh*64 + d
  int bh = g >> 6, d = g & 63;
  const float* rp = rsbuf + (long)bh * 16 * 64 + d;
  float s = 0.f;
#pragma unroll
  for (int c = 0; c < 16; c++) s += rp[c * 64];
  kinvz[g] = 1.0f / s;
}

// ---------------------------------------------------------------------------
// M_b[c][h*64+d] = SCALE * invZ[bh][d] * sum_e w_out[c][h*64+e] * ctx[bh][d][e]
// ---------------------------------------------------------------------------
__global__ __launch_bounds__(256) void mctx_kernel(const float* __restrict__ w_out,
                                                   const float* __restrict__ ctx,
                                                   const float* __restrict__ kinvz,
                                                   _Float16* __restrict__ Mhi,
                                                   _Float16* __restrict__ Mlo) {
  __shared__ float sctxT[64][65];  // [e][d], +1 pad
  const int cq = blockIdx.x, h = blockIdx.y, b = blockIdx.z;
  const int bh = b * 4 + h;
  const float* cp = ctx + (long)bh * 4096;  // [d][e]
  const int tid = threadIdx.x;
  {
    const int d = tid >> 2, e0 = (tid & 3) * 16;
#pragma unroll
    for (int k = 0; k < 4; k++) {
      float4 v = *(const float4*)&cp[d * 64 + e0 + k * 4];
      sctxT[e0 + k * 4 + 0][d] = v.x;
      sctxT[e0 + k * 4 + 1][d] = v.y;
      sctxT[e0 + k * 4 + 2][d] = v.z;
      sctxT[e0 + k * 4 + 3][d] = v.w;
    }
  }
  __syncthreads();
  const int c = cq * 64 + (tid >> 2);
  const int d0 = (tid & 3) * 16;
  const float* wp = w_out + (long)c * 256 + h * 64;
  float acc[16];
#pragma unroll
  for (int i = 0; i < 16; i++) acc[i] = 0.f;
#pragma unroll
  for (int e4 = 0; e4 < 16; e4++) {
    float4 wv = *(const float4*)&wp[e4 * 4];
#pragma unroll
    for (int u2 = 0; u2 < 4; u2++) {
      const float we = ((const float*)&wv)[u2];
      const int e = e4 * 4 + u2;
#pragma unroll
      for (int dd = 0; dd < 16; dd++) acc[dd] = fmaf(we, sctxT[e][d0 + dd], acc[dd]);
    }
  }
  alignas(16) _Float16 hi16[16], lo16[16];
#pragma unroll
  for (int k4 = 0; k4 < 4; k4++) {
    float4 zv = *(const float4*)&kinvz[bh * 64 + d0 + k4 * 4];
#pragma unroll
    for (int u2 = 0; u2 < 4; u2++) {
      const int dd = k4 * 4 + u2;
      float v = acc[dd] * (SCALE * ((const float*)&zv)[u2]);
      _Float16 hh = (_Float16)v;
      hi16[dd] = hh;
      lo16[dd] = (_Float16)(v - (float)hh);
    }
  }
  _Float16* mh = Mhi + ((long)b * 256 + c) * 256 + h * 64 + d0;
  _Float16* ml = Mlo + ((long)b * 256 + c) * 256 + h * 64 + d0;
#pragma unroll
  for (int k = 0; k < 2; k++) {
    *(float4*)&mh[k * 8] = *(float4*)&hi16[k * 8];
    *(float4*)&ml[k * 8] = *(float4*)&lo16[k * 8];
  }
}

// ---------------------------------------------------------------------------
// final GEMM: out[b][256][4096] = (Mhi+Mlo)[b] @ PT[b]^T + b_out
// B layout: PT[b][s][4096][128], s = K-half (kt>>2). 512-thr, BN=256.
// ---------------------------------------------------------------------------
__global__ __launch_bounds__(512, 4) void out_gemm(const _Float16* __restrict__ Mhi,
                                                   const _Float16* __restrict__ Mlo,
                                                   const _Float16* __restrict__ PT,
                                                   float* __restrict__ C,
                                                   const float* __restrict__ bias) {
  __shared__ _Float16 st[2][16384];  // 64 KB dbuf staging
  const int tid = threadIdx.x;
  const int n0 = blockIdx.x * 256, m0 = blockIdx.y * 128;
  const int b = blockIdx.z;
  const _Float16* Ah = Mhi + (long)b * 65536;
  const _Float16* Al = Mlo + (long)b * 65536;
  float* Cp = C + (long)b * 256 * NPIX;
  const int wv = tid >> 6, l = tid & 63;
  const int r16 = l & 15, q = l >> 4;
  const int mb = (wv >> 2) * 64, nb = (wv & 3) * 64;
  const int r1 = tid >> 2;  // 0..127
  const int o1 = ((tid & 3) * 8) ^ (((r1 >> 1) & 3) * 8);
  const int ldsA = wv * 512;
  const int q8 = (q * 8) ^ (((r16 >> 1) & 3) * 8);

  auto STAGE = [&](int buf, int kt) {
    const int k0 = kt * 32;
    _Float16* base = st[buf];
    async16(&base[ldsA], &Ah[(long)(m0 + r1) * 256 + k0 + o1]);
    async16(&base[4096 + ldsA], &Al[(long)(m0 + r1) * 256 + k0 + o1]);
    const _Float16* Bk = PT + ((long)(b * 2 + (kt >> 2)) * NPIX + n0) * 128;
    async16(&base[8192 + ldsA], &Bk[(long)r1 * 128 + (kt & 3) * 32 + o1]);
    async16(&base[12288 + ldsA], &Bk[(long)(r1 + 128) * 128 + (kt & 3) * 32 + o1]);
  };

  floatx4 acc[4][4];
#pragma unroll
  for (int i = 0; i < 4; i++)
#pragma unroll
    for (int j = 0; j < 4; j++) acc[i][j] = (floatx4){0.f, 0.f, 0.f, 0.f};

  STAGE(0, 0);
  __syncthreads();
  int cur = 0;
  for (int kt = 0; kt < 8; kt++) {
    if (kt < 7) STAGE(cur ^ 1, kt + 1);
    half8 fa[4], flo[4], fb[4];
#pragma unroll
    for (int i = 0; i < 4; i++) {
      fa[i] = *(const half8*)&st[cur][(mb + i * 16 + r16) * 32 + q8];
      flo[i] = *(const half8*)&st[cur][4096 + (mb + i * 16 + r16) * 32 + q8];
      fb[i] = *(const half8*)&st[cur][8192 + (nb + i * 16 + r16) * 32 + q8];
    }
#pragma unroll
    for (int i = 0; i < 4; i++)
#pragma unroll
      for (int j = 0; j < 4; j++) {
        acc[i][j] = __builtin_amdgcn_mfma_f32_16x16x32_f16(fa[i], fb[j], acc[i][j], 0, 0, 0);
        acc[i][j] = __builtin_amdgcn_mfma_f32_16x16x32_f16(flo[i], fb[j], acc[i][j], 0, 0, 0);
      }
    __syncthreads();
    cur ^= 1;
  }
#pragma unroll
  for (int i = 0; i < 4; i++) {
    const int mrow = m0 + mb + i * 16 + q * 4;
#pragma unroll
    for (int t = 0; t < 4; t++) {
      float bz = bias[mrow + t];
#pragma unroll
      for (int j = 0; j < 4; j++) {
        Cp[(long)(mrow + t) * NPIX + n0 + nb + j * 16 + r16] = acc[i][j][t] + bz;
      }
    }
  }
}

extern "C" void kernel_launch(void* const* d_in, const int* in_sizes, int n_in,
                              void* d_out, int out_size, void* d_ws, size_t ws_size,
                              hipStream_t stream) {
  const float* x = (const float*)d_in[0];      // [16][256][4096]
  const float* w_qkv = (const float*)d_in[1];  // [768][256]
  const float* w_out = (const float*)d_in[2];  // [256][256]
  const float* b_out = (const float*)d_in[3];  // [256]
  float* out = (float*)d_out;                  // [16][256][4096]

  // d_ws layout (all live ranges disjoint in time or space):
  _Float16* PT = (_Float16*)d_ws;                           // [16][2][4096][128] = 32 MB
  float* ctx = (float*)(PT + (long)16 * 2 * NPIX * 128);    // 64bh * 4096 = 1 MB
  float* kinvz = ctx + 64 * 4096;                           // 16 KB
  float* rsbuf = kinvz + 4096;                              // 64bh*16p*64 = 256 KB
  _Float16* wq_hi = (_Float16*)(rsbuf + 64 * 16 * 64);
  _Float16* wq_lo = wq_hi + 768 * 256;
  _Float16* Mhi = wq_lo + 768 * 256;                        // 16*256*256 fp16 = 2 MB
  _Float16* Mlo = Mhi + 16 * 256 * 256;                     // 2 MB
  // d_out scratch (dead until out_gemm writes it):
  _Float16* xt = (_Float16*)d_out;                          // [0..32MB)
  float* pbuf = (float*)d_out + (1 << 23);                  // [32MB..48MB): 64bh*16p*4096

  split16_kernel<<<768, 256, 0, stream>>>(w_qkv, wq_hi, wq_lo, 768 * 256);
  transpose16_kernel<<<dim3(64, 4, 16), 256, 0, stream>>>(x, xt);
  // fused k/v GEMM + exp(k)@v^T context partials (2x256-n chunks/block)
  kv_ctx_gemm<<<dim3(8, 4, 16), 512, 0, stream>>>(wq_hi, wq_lo, xt, pbuf, rsbuf);
  reduce_ctx<<<1024, 256, 0, stream>>>(pbuf, ctx);
  zinv_kernel<<<16, 256, 0, stream>>>(rsbuf, kinvz);
  // fused q GEMM + softmax -> P fp16 (q fp32 never touches HBM)
  q_gemm_softmax<<<dim3(16, 2, 16), 512, 0, stream>>>(wq_hi, wq_lo, xt, PT);
  // M_b = w_out @ ctx^T * diag(SCALE*invZ): attention folded into final A
  mctx_kernel<<<dim3(4, 4, 16), 256, 0, stream>>>(w_out, ctx, kinvz, Mhi, Mlo);
  // final = M_b @ P_b + b_out
  out_gemm<<<dim3(16, 2, 16), 512, 0, stream>>>(Mhi, Mlo, PT, out, b_out);
}

// Round 5
// 222.172 us; speedup vs baseline: 1.1453x; 1.1453x over previous
//
#include <hip/hip_runtime.h>

#define NPIX 4096
#define SCALE 0.125f

typedef _Float16 half8 __attribute__((ext_vector_type(8)));
typedef _Float16 half4 __attribute__((ext_vector_type(4)));
typedef float floatx4 __attribute__((ext_vector_type(4)));

// async global->LDS, 16B per lane. lds base must be wave-uniform; data lands
// at base + lane*16 (gfx950 semantics, learn_hip m97/m104).
__device__ __forceinline__ void async16(void* lds, const void* g) {
  __builtin_amdgcn_global_load_lds(
      (const __attribute__((address_space(1))) unsigned int*)(uintptr_t)g,
      (__attribute__((address_space(3))) unsigned int*)(unsigned)(uintptr_t)lds,
      16, 0, 0);
}

// ---------------------------------------------------------------------------
// split fp32 -> hi/lo fp16 (a = hi + lo, ~21 mantissa bits kept)
// ---------------------------------------------------------------------------
__global__ __launch_bounds__(256) void split16_kernel(const float* __restrict__ w,
                                                      _Float16* __restrict__ hi,
                                                      _Float16* __restrict__ lo, int n) {
  int i = blockIdx.x * 256 + threadIdx.x;
  if (i < n) {
    float v = w[i];
    _Float16 h = (_Float16)v;
    hi[i] = h;
    lo[i] = (_Float16)(v - (float)h);
  }
}

// ---------------------------------------------------------------------------
// x[b][256][4096] fp32 -> xt[b][4096][256] fp16 (K-contiguous for B-operand)
// ---------------------------------------------------------------------------
__global__ __launch_bounds__(256) void transpose16_kernel(const float* __restrict__ x,
                                                          _Float16* __restrict__ xt) {
  __shared__ float t[64][65];
  const int n0 = blockIdx.x * 64, c0 = blockIdx.y * 64, b = blockIdx.z;
  const float* xp = x + (long)b * 256 * NPIX;
  const int tid = threadIdx.x;
  const int r = tid >> 4, c4 = (tid & 15) * 4;
#pragma unroll
  for (int p = 0; p < 4; p++) {
    float4 v = *(const float4*)&xp[(long)(c0 + r + p * 16) * NPIX + n0 + c4];
    t[r + p * 16][c4 + 0] = v.x;
    t[r + p * 16][c4 + 1] = v.y;
    t[r + p * 16][c4 + 2] = v.z;
    t[r + p * 16][c4 + 3] = v.w;
  }
  __syncthreads();
  const int n = tid >> 2, cg = (tid & 3) * 16;
  alignas(16) _Float16 o[16];
#pragma unroll
  for (int i = 0; i < 16; i++) o[i] = (_Float16)t[cg + i][n];
  _Float16* dst = &xt[((long)b * NPIX + n0 + n) * 256 + c0 + cg];
  *(float4*)dst = *(float4*)&o[0];
  *(float4*)(dst + 8) = *(float4*)&o[8];
}

// ---------------------------------------------------------------------------
// FUSED q-GEMM + column softmax over d. 2-phase prefetch double-buffered
// staging: STAGE(t+1) issued before ds_read/MFMA of tile t; the single
// __syncthreads (drains vmcnt+lgkm) at loop bottom is the only barrier.
// 256 thr / 48KB LDS / 128 VGPR -> 3 blocks/CU.
// ---------------------------------------------------------------------------
__global__ __launch_bounds__(256) void q_gemm_softmax(const _Float16* __restrict__ Ahp,
                                                      const _Float16* __restrict__ Alp,
                                                      const _Float16* __restrict__ Bt,
                                                      _Float16* __restrict__ PT) {
  union alignas(16) QU {
    _Float16 st[2][3][128 * 32];  // [buf][Ah,Al,Bt] 48 KB dbuf staging
    _Float16 pt[128][128];        // 32 KB, epilogue P-tile (XOR-swizzled cols)
  };
  __shared__ QU u;
  const int tid = threadIdx.x;
  const int n0 = blockIdx.x * 128, m0 = blockIdx.y * 128;
  const int bz = blockIdx.z;
  const _Float16* Bp = Bt + (long)bz * NPIX * 256;
  const int wv = tid >> 6, l = tid & 63;
  const int r16 = l & 15, q = l >> 4;
  const int mb = (wv >> 1) * 64, nb = (wv & 1) * 64;
  const int r1 = tid >> 2;
  const int o1 = ((tid & 3) * 8) ^ (((r1 >> 1) & 3) * 8);
  const int r2 = r1 + 64;
  const int ldsc1 = (wv * 64) * 8;
  const int ldsc2 = (256 + wv * 64) * 8;
  const int q8 = (q * 8) ^ (((r16 >> 1) & 3) * 8);

  auto STAGE = [&](int buf, int kt) {
    const int k0 = kt * 32;
    async16(&u.st[buf][0][ldsc1], &Ahp[(long)(m0 + r1) * 256 + k0 + o1]);
    async16(&u.st[buf][0][ldsc2], &Ahp[(long)(m0 + r2) * 256 + k0 + o1]);
    async16(&u.st[buf][1][ldsc1], &Alp[(long)(m0 + r1) * 256 + k0 + o1]);
    async16(&u.st[buf][1][ldsc2], &Alp[(long)(m0 + r2) * 256 + k0 + o1]);
    async16(&u.st[buf][2][ldsc1], &Bp[(long)(n0 + r1) * 256 + k0 + o1]);
    async16(&u.st[buf][2][ldsc2], &Bp[(long)(n0 + r2) * 256 + k0 + o1]);
  };

  floatx4 acc[4][4];
#pragma unroll
  for (int i = 0; i < 4; i++)
#pragma unroll
    for (int j = 0; j < 4; j++) acc[i][j] = (floatx4){0.f, 0.f, 0.f, 0.f};

  STAGE(0, 0);
  __syncthreads();
  int cur = 0;
  for (int kt = 0; kt < 8; kt++) {
    if (kt < 7) STAGE(cur ^ 1, kt + 1);
    half8 fa[4], flo[4], fb[4];
#pragma unroll
    for (int i = 0; i < 4; i++) {
      fa[i] = *(const half8*)&u.st[cur][0][(mb + i * 16 + r16) * 32 + q8];
      flo[i] = *(const half8*)&u.st[cur][1][(mb + i * 16 + r16) * 32 + q8];
      fb[i] = *(const half8*)&u.st[cur][2][(nb + i * 16 + r16) * 32 + q8];
    }
#pragma unroll
    for (int i = 0; i < 4; i++)
#pragma unroll
      for (int j = 0; j < 4; j++) {
        acc[i][j] = __builtin_amdgcn_mfma_f32_16x16x32_f16(fa[i], fb[j], acc[i][j], 0, 0, 0);
        acc[i][j] = __builtin_amdgcn_mfma_f32_16x16x32_f16(flo[i], fb[j], acc[i][j], 0, 0, 0);
      }
    __syncthreads();
    cur ^= 1;
  }

  // ---- epilogue: per-column softmax over d (wave holds one head's 64 rows) ----
#pragma unroll
  for (int j = 0; j < 4; j++) {
    float s = 0.f;
#pragma unroll
    for (int i = 0; i < 4; i++)
#pragma unroll
      for (int t = 0; t < 4; t++) {
        float e = __expf(acc[i][j][t]);
        acc[i][j][t] = e;
        s += e;
      }
    s += __shfl_xor(s, 16, 64);
    s += __shfl_xor(s, 32, 64);
    const float rinv = 1.0f / s;
    const int nl = nb + j * 16 + r16;
    const int swz = (nl & 7) * 8;  // bank-spread: (q,nl&7) -> 32 distinct banks
#pragma unroll
    for (int i = 0; i < 4; i++) {
      half4 h4;
#pragma unroll
      for (int t = 0; t < 4; t++) h4[t] = (_Float16)(acc[i][j][t] * rinv);
      *(half4*)&u.pt[nl][(mb + i * 16 + q * 4) ^ swz] = h4;
    }
  }
  __syncthreads();
  // ---- dump P-tile: rows contiguous (PT row stride = 128 c), 1KB/wave-instr ----
  const int rbase = tid >> 4, c16 = tid & 15;
  _Float16* dst = PT + ((long)(bz * 2 + (m0 >> 7)) * NPIX + n0) * 128;
#pragma unroll
  for (int k = 0; k < 8; k++) {
    const int row = rbase + k * 16;
    const int chunk = c16 ^ (row & 7);
    float4 v = *(const float4*)&u.pt[row][chunk * 8];
    *(float4*)&dst[(long)row * 128 + c16 * 8] = v;
  }
}

// ---------------------------------------------------------------------------
// FUSED k/v GEMM + exp(k)@v^T context partials. CPB=2 n-chunks per block,
// c2 accumulates in MFMA C-regs across chunks. Grid 16x4x16 = 1024 blocks
// (4/CU demand, 3/CU resident by 48KB LDS) -- round 3 was grid-starved at
// 2/CU. 256 thr / 128 VGPR: no spill (round-4 lesson: 512-thr bounds forced
// VGPR=64 -> 100MB of scratch traffic).
// ---------------------------------------------------------------------------
#define CPB 2
__global__ __launch_bounds__(256) void kv_ctx_gemm(const _Float16* __restrict__ Ahp,
                                                   const _Float16* __restrict__ Alp,
                                                   const _Float16* __restrict__ Bt,
                                                   float* __restrict__ pbuf,
                                                   float* __restrict__ rsbuf) {
  union alignas(16) KVU {
    _Float16 st[2][3][128 * 32];  // 48 KB dbuf staging
    _Float16 ev[128][136];        // 34 KB epilogue: rows 0..63 exp(k), 64..127 v
  };
  __shared__ KVU u;
  const int tid = threadIdx.x;
  const int cg = blockIdx.x;     // 0..15 chunk-group (2 chunks of 128 each)
  const int hi = blockIdx.y;     // head 0..3
  const int b = blockIdx.z;
  const _Float16* Bp = Bt + (long)b * NPIX * 256;
  const int wv = tid >> 6, l = tid & 63;
  const int r16 = l & 15, q = l >> 4;
  const int mb = (wv >> 1) * 64, nb = (wv & 1) * 64;
  const int r1 = tid >> 2;
  const int o1 = ((tid & 3) * 8) ^ (((r1 >> 1) & 3) * 8);
  const int ldsc1 = (wv * 64) * 8;
  const int ldsc2 = (256 + wv * 64) * 8;
  const int q8 = (q * 8) ^ (((r16 >> 1) & 3) * 8);
  // A rows: local 0..63 = k[head hi], 64..127 = v[head hi]
  const long gAk = (long)(256 + hi * 64 + r1) * 256;
  const long gAv = (long)(512 + hi * 64 + r1) * 256;

  auto STAGE = [&](int buf, int kt, int n0) {
    const int k0 = kt * 32;
    async16(&u.st[buf][0][ldsc1], &Ahp[gAk + k0 + o1]);
    async16(&u.st[buf][0][ldsc2], &Ahp[gAv + k0 + o1]);
    async16(&u.st[buf][1][ldsc1], &Alp[gAk + k0 + o1]);
    async16(&u.st[buf][1][ldsc2], &Alp[gAv + k0 + o1]);
    async16(&u.st[buf][2][ldsc1], &Bp[(long)(n0 + r1) * 256 + k0 + o1]);
    async16(&u.st[buf][2][ldsc2], &Bp[(long)(n0 + 64 + r1) * 256 + k0 + o1]);
  };

  floatx4 c2[4];
#pragma unroll
  for (int j = 0; j < 4; j++) c2[j] = (floatx4){0.f, 0.f, 0.f, 0.f};
  float rs = 0.f;

  for (int cs = 0; cs < CPB; cs++) {
    const int n0 = (cg * CPB + cs) * 128;
    floatx4 acc[4][4];
#pragma unroll
    for (int i = 0; i < 4; i++)
#pragma unroll
      for (int j = 0; j < 4; j++) acc[i][j] = (floatx4){0.f, 0.f, 0.f, 0.f};

    STAGE(0, 0, n0);
    __syncthreads();
    int cur = 0;
    for (int kt = 0; kt < 8; kt++) {
      if (kt < 7) STAGE(cur ^ 1, kt + 1, n0);
      half8 fa[4], flo[4], fb[4];
#pragma unroll
      for (int i = 0; i < 4; i++) {
        fa[i] = *(const half8*)&u.st[cur][0][(mb + i * 16 + r16) * 32 + q8];
        flo[i] = *(const half8*)&u.st[cur][1][(mb + i * 16 + r16) * 32 + q8];
        fb[i] = *(const half8*)&u.st[cur][2][(nb + i * 16 + r16) * 32 + q8];
      }
#pragma unroll
      for (int i = 0; i < 4; i++)
#pragma unroll
        for (int j = 0; j < 4; j++) {
          acc[i][j] = __builtin_amdgcn_mfma_f32_16x16x32_f16(fa[i], fb[j], acc[i][j], 0, 0, 0);
          acc[i][j] = __builtin_amdgcn_mfma_f32_16x16x32_f16(flo[i], fb[j], acc[i][j], 0, 0, 0);
        }
      __syncthreads();
      cur ^= 1;
    }

    // ---- epilogue: acc -> exp(k)/v fp16 tile in LDS (stride 136) ----
    const bool is_k = (mb == 0);
#pragma unroll
    for (int i = 0; i < 4; i++) {
      const int row = mb + i * 16 + q * 4;
#pragma unroll
      for (int j = 0; j < 4; j++) {
        const int col = nb + j * 16 + r16;
#pragma unroll
        for (int t = 0; t < 4; t++) {
          const float vv0 = acc[i][j][t];
          u.ev[row + t][col] = (_Float16)(is_k ? __expf(vv0) : vv0);
        }
      }
    }
    __syncthreads();

    // ---- context partial: c2[d][e] += sum_n exp(k[d][n]) v[e][n], K=128 ----
#pragma unroll
    for (int ks = 0; ks < 4; ks++) {
      half8 a = *(const half8*)&u.ev[wv * 16 + r16][ks * 32 + q * 8];
#pragma unroll
      for (int ii = 0; ii < 8; ii++) rs += (float)a[ii];
#pragma unroll
      for (int j = 0; j < 4; j++) {
        half8 bv = *(const half8*)&u.ev[64 + j * 16 + r16][ks * 32 + q * 8];
        c2[j] = __builtin_amdgcn_mfma_f32_16x16x32_f16(a, bv, c2[j], 0, 0, 0);
      }
    }
    __syncthreads();  // ev reads done before next chunk's STAGE overwrites
  }

  rs += __shfl_xor(rs, 16, 64);
  rs += __shfl_xor(rs, 32, 64);
  const int bh = b * 4 + hi;
  float* pp = pbuf + ((long)bh * 16 + cg) * 4096;
#pragma unroll
  for (int j = 0; j < 4; j++)
#pragma unroll
    for (int reg = 0; reg < 4; reg++)
      pp[(wv * 16 + q * 4 + reg) * 64 + j * 16 + r16] = c2[j][reg];
  if (l < 16) rsbuf[((long)bh * 16 + cg) * 64 + wv * 16 + r16] = rs;
}

// ---------------------------------------------------------------------------
// ctx[bh][4096] = sum over 16 chunk-group partials (deterministic, no atomics)
// ---------------------------------------------------------------------------
__global__ __launch_bounds__(256) void reduce_ctx(const float* __restrict__ pbuf,
                                                  float* __restrict__ ctx) {
  int g = blockIdx.x * 256 + threadIdx.x;  // 0..262143
  int bh = g >> 12, e = g & 4095;
  const float* pp = pbuf + ((long)bh * 16) * 4096 + e;
  float s = 0.f;
#pragma unroll
  for (int c = 0; c < 16; c++) s += pp[(long)c * 4096];
  ctx[g] = s;
}

// ---------------------------------------------------------------------------
// kinvz[bh*64+d] = 1 / sum over 16 chunk-group row-sums
// ---------------------------------------------------------------------------
__global__ __launch_bounds__(256) void zinv_kernel(const float* __restrict__ rsbuf,
                                                   float* __restrict__ kinvz) {
  int g = blockIdx.x * 256 + threadIdx.x;  // 0..4095 = bh*64 + d
  int bh = g >> 6, d = g & 63;
  const float* rp = rsbuf + (long)bh * 16 * 64 + d;
  float s = 0.f;
#pragma unroll
  for (int c = 0; c < 16; c++) s += rp[c * 64];
  kinvz[g] = 1.0f / s;
}

// ---------------------------------------------------------------------------
// M_b[c][h*64+d] = SCALE * invZ[bh][d] * sum_e w_out[c][h*64+e] * ctx[bh][d][e]
// (folds the attention d-contraction into the final GEMM's A-operand).
// ---------------------------------------------------------------------------
__global__ __launch_bounds__(256) void mctx_kernel(const float* __restrict__ w_out,
                                                   const float* __restrict__ ctx,
                                                   const float* __restrict__ kinvz,
                                                   _Float16* __restrict__ Mhi,
                                                   _Float16* __restrict__ Mlo) {
  __shared__ float sctxT[64][65];  // [e][d], +1 pad
  const int cq = blockIdx.x, h = blockIdx.y, b = blockIdx.z;
  const int bh = b * 4 + h;
  const float* cp = ctx + (long)bh * 4096;  // [d][e]
  const int tid = threadIdx.x;
  {
    const int d = tid >> 2, e0 = (tid & 3) * 16;
#pragma unroll
    for (int k = 0; k < 4; k++) {
      float4 v = *(const float4*)&cp[d * 64 + e0 + k * 4];
      sctxT[e0 + k * 4 + 0][d] = v.x;
      sctxT[e0 + k * 4 + 1][d] = v.y;
      sctxT[e0 + k * 4 + 2][d] = v.z;
      sctxT[e0 + k * 4 + 3][d] = v.w;
    }
  }
  __syncthreads();
  const int c = cq * 64 + (tid >> 2);
  const int d0 = (tid & 3) * 16;
  const float* wp = w_out + (long)c * 256 + h * 64;
  float acc[16];
#pragma unroll
  for (int i = 0; i < 16; i++) acc[i] = 0.f;
#pragma unroll
  for (int e4 = 0; e4 < 16; e4++) {
    float4 wv = *(const float4*)&wp[e4 * 4];
#pragma unroll
    for (int u2 = 0; u2 < 4; u2++) {
      const float we = ((const float*)&wv)[u2];
      const int e = e4 * 4 + u2;
#pragma unroll
      for (int dd = 0; dd < 16; dd++) acc[dd] = fmaf(we, sctxT[e][d0 + dd], acc[dd]);
    }
  }
  alignas(16) _Float16 hi16[16], lo16[16];
#pragma unroll
  for (int k4 = 0; k4 < 4; k4++) {
    float4 zv = *(const float4*)&kinvz[bh * 64 + d0 + k4 * 4];
#pragma unroll
    for (int u2 = 0; u2 < 4; u2++) {
      const int dd = k4 * 4 + u2;
      float v = acc[dd] * (SCALE * ((const float*)&zv)[u2]);
      _Float16 hh = (_Float16)v;
      hi16[dd] = hh;
      lo16[dd] = (_Float16)(v - (float)hh);
    }
  }
  _Float16* mh = Mhi + ((long)b * 256 + c) * 256 + h * 64 + d0;
  _Float16* ml = Mlo + ((long)b * 256 + c) * 256 + h * 64 + d0;
#pragma unroll
  for (int k = 0; k < 2; k++) {
    *(float4*)&mh[k * 8] = *(float4*)&hi16[k * 8];
    *(float4*)&ml[k * 8] = *(float4*)&lo16[k * 8];
  }
}

// ---------------------------------------------------------------------------
// final GEMM: out[b][256][4096] = (Mhi+Mlo)[b] @ PT[b]^T + b_out
// B layout: PT[b][s][4096][128], s = K-half (kt>>2). 2-phase prefetch.
// ---------------------------------------------------------------------------
__global__ __launch_bounds__(256) void out_gemm(const _Float16* __restrict__ Mhi,
                                                const _Float16* __restrict__ Mlo,
                                                const _Float16* __restrict__ PT,
                                                float* __restrict__ C,
                                                const float* __restrict__ bias) {
  __shared__ _Float16 st[2][3][128 * 32];  // 48 KB dbuf staging
  const int tid = threadIdx.x;
  const int n0 = blockIdx.x * 128, m0 = blockIdx.y * 128;
  const int b = blockIdx.z;
  const _Float16* Ah = Mhi + (long)b * 65536;
  const _Float16* Al = Mlo + (long)b * 65536;
  float* Cp = C + (long)b * 256 * NPIX;
  const int wv = tid >> 6, l = tid & 63;
  const int r16 = l & 15, q = l >> 4;
  const int mb = (wv >> 1) * 64, nb = (wv & 1) * 64;
  const int r1 = tid >> 2;
  const int o1 = ((tid & 3) * 8) ^ (((r1 >> 1) & 3) * 8);
  const int r2 = r1 + 64;
  const int ldsc1 = (wv * 64) * 8;
  const int ldsc2 = (256 + wv * 64) * 8;
  const int q8 = (q * 8) ^ (((r16 >> 1) & 3) * 8);

  auto STAGE = [&](int buf, int kt) {
    const int k0 = kt * 32;
    async16(&st[buf][0][ldsc1], &Ah[(long)(m0 + r1) * 256 + k0 + o1]);
    async16(&st[buf][0][ldsc2], &Ah[(long)(m0 + r2) * 256 + k0 + o1]);
    async16(&st[buf][1][ldsc1], &Al[(long)(m0 + r1) * 256 + k0 + o1]);
    async16(&st[buf][1][ldsc2], &Al[(long)(m0 + r2) * 256 + k0 + o1]);
    const _Float16* Bk = PT + ((long)(b * 2 + (kt >> 2)) * NPIX + n0) * 128;
    async16(&st[buf][2][ldsc1], &Bk[(long)r1 * 128 + (kt & 3) * 32 + o1]);
    async16(&st[buf][2][ldsc2], &Bk[(long)(r1 + 64) * 128 + (kt & 3) * 32 + o1]);
  };

  floatx4 acc[4][4];
#pragma unroll
  for (int i = 0; i < 4; i++)
#pragma unroll
    for (int j = 0; j < 4; j++) acc[i][j] = (floatx4){0.f, 0.f, 0.f, 0.f};

  STAGE(0, 0);
  __syncthreads();
  int cur = 0;
  for (int kt = 0; kt < 8; kt++) {
    if (kt < 7) STAGE(cur ^ 1, kt + 1);
    half8 fa[4], flo[4], fb[4];
#pragma unroll
    for (int i = 0; i < 4; i++) {
      fa[i] = *(const half8*)&st[cur][0][(mb + i * 16 + r16) * 32 + q8];
      flo[i] = *(const half8*)&st[cur][1][(mb + i * 16 + r16) * 32 + q8];
      fb[i] = *(const half8*)&st[cur][2][(nb + i * 16 + r16) * 32 + q8];
    }
#pragma unroll
    for (int i = 0; i < 4; i++)
#pragma unroll
      for (int j = 0; j < 4; j++) {
        acc[i][j] = __builtin_amdgcn_mfma_f32_16x16x32_f16(fa[i], fb[j], acc[i][j], 0, 0, 0);
        acc[i][j] = __builtin_amdgcn_mfma_f32_16x16x32_f16(flo[i], fb[j], acc[i][j], 0, 0, 0);
      }
    __syncthreads();
    cur ^= 1;
  }
#pragma unroll
  for (int i = 0; i < 4; i++) {
    const int mrow = m0 + mb + i * 16 + q * 4;
#pragma unroll
    for (int t = 0; t < 4; t++) {
      float bz = bias[mrow + t];
#pragma unroll
      for (int j = 0; j < 4; j++) {
        Cp[(long)(mrow + t) * NPIX + n0 + nb + j * 16 + r16] = acc[i][j][t] + bz;
      }
    }
  }
}

extern "C" void kernel_launch(void* const* d_in, const int* in_sizes, int n_in,
                              void* d_out, int out_size, void* d_ws, size_t ws_size,
                              hipStream_t stream) {
  const float* x = (const float*)d_in[0];      // [16][256][4096]
  const float* w_qkv = (const float*)d_in[1];  // [768][256]
  const float* w_out = (const float*)d_in[2];  // [256][256]
  const float* b_out = (const float*)d_in[3];  // [256]
  float* out = (float*)d_out;                  // [16][256][4096]

  // d_ws layout (all live ranges disjoint in time or space):
  _Float16* PT = (_Float16*)d_ws;                           // [16][2][4096][128] = 32 MB
  float* ctx = (float*)(PT + (long)16 * 2 * NPIX * 128);    // 64bh * 4096 = 1 MB
  float* kinvz = ctx + 64 * 4096;                           // 16 KB
  float* rsbuf = kinvz + 4096;                              // 64bh*16p*64 = 256 KB
  _Float16* wq_hi = (_Float16*)(rsbuf + 64 * 16 * 64);
  _Float16* wq_lo = wq_hi + 768 * 256;
  _Float16* Mhi = wq_lo + 768 * 256;                        // 16*256*256 fp16 = 2 MB
  _Float16* Mlo = Mhi + 16 * 256 * 256;                     // 2 MB
  // d_out scratch (dead until out_gemm writes it):
  _Float16* xt = (_Float16*)d_out;                          // [0..32MB)
  float* pbuf = (float*)d_out + (1 << 23);                  // [32MB..48MB): 64bh*16p*4096

  split16_kernel<<<768, 256, 0, stream>>>(w_qkv, wq_hi, wq_lo, 768 * 256);
  transpose16_kernel<<<dim3(64, 4, 16), 256, 0, stream>>>(x, xt);
  // fused k/v GEMM + exp(k)@v^T context partials (2 chunks/block, reg-accum)
  kv_ctx_gemm<<<dim3(16, 4, 16), 256, 0, stream>>>(wq_hi, wq_lo, xt, pbuf, rsbuf);
  reduce_ctx<<<1024, 256, 0, stream>>>(pbuf, ctx);
  zinv_kernel<<<16, 256, 0, stream>>>(rsbuf, kinvz);
  // fused q GEMM + softmax -> P fp16 (q fp32 never touches HBM)
  q_gemm_softmax<<<dim3(32, 2, 16), 256, 0, stream>>>(wq_hi, wq_lo, xt, PT);
  // M_b = w_out @ ctx^T * diag(SCALE*invZ): attention folded into final A
  mctx_kernel<<<dim3(4, 4, 16), 256, 0, stream>>>(w_out, ctx, kinvz, Mhi, Mlo);
  // final = M_b @ P_b + b_out
  out_gemm<<<dim3(32, 2, 16), 256, 0, stream>>>(Mhi, Mlo, PT, out, b_out);
}

// Round 6
// 208.435 us; speedup vs baseline: 1.2208x; 1.0659x over previous
//
#include <hip/hip_runtime.h>

#define NPIX 4096
#define SCALE 0.125f

typedef _Float16 half8 __attribute__((ext_vector_type(8)));
typedef _Float16 half4 __attribute__((ext_vector_type(4)));
typedef float floatx4 __attribute__((ext_vector_type(4)));

// async global->LDS, 16B per lane. lds base must be wave-uniform; data lands
// at base + lane*16 (gfx950 semantics, learn_hip m97/m104).
__device__ __forceinline__ void async16(void* lds, const void* g) {
  __builtin_amdgcn_global_load_lds(
      (const __attribute__((address_space(1))) unsigned int*)(uintptr_t)g,
      (__attribute__((address_space(3))) unsigned int*)(unsigned)(uintptr_t)lds,
      16, 0, 0);
}

// ---------------------------------------------------------------------------
// split fp32 -> hi/lo fp16 (a = hi + lo, ~21 mantissa bits kept)
// ---------------------------------------------------------------------------
__global__ __launch_bounds__(256) void split16_kernel(const float* __restrict__ w,
                                                      _Float16* __restrict__ hi,
                                                      _Float16* __restrict__ lo, int n) {
  int i = blockIdx.x * 256 + threadIdx.x;
  if (i < n) {
    float v = w[i];
    _Float16 h = (_Float16)v;
    hi[i] = h;
    lo[i] = (_Float16)(v - (float)h);
  }
}

// ---------------------------------------------------------------------------
// x[b][256][4096] fp32 -> xt[b][4096][256] fp16 (K-contiguous for B-operand)
// ---------------------------------------------------------------------------
__global__ __launch_bounds__(256) void transpose16_kernel(const float* __restrict__ x,
                                                          _Float16* __restrict__ xt) {
  __shared__ float t[64][65];
  const int n0 = blockIdx.x * 64, c0 = blockIdx.y * 64, b = blockIdx.z;
  const float* xp = x + (long)b * 256 * NPIX;
  const int tid = threadIdx.x;
  const int r = tid >> 4, c4 = (tid & 15) * 4;
#pragma unroll
  for (int p = 0; p < 4; p++) {
    float4 v = *(const float4*)&xp[(long)(c0 + r + p * 16) * NPIX + n0 + c4];
    t[r + p * 16][c4 + 0] = v.x;
    t[r + p * 16][c4 + 1] = v.y;
    t[r + p * 16][c4 + 2] = v.z;
    t[r + p * 16][c4 + 3] = v.w;
  }
  __syncthreads();
  const int n = tid >> 2, cg = (tid & 3) * 16;
  alignas(16) _Float16 o[16];
#pragma unroll
  for (int i = 0; i < 16; i++) o[i] = (_Float16)t[cg + i][n];
  _Float16* dst = &xt[((long)b * NPIX + n0 + n) * 256 + c0 + cg];
  *(float4*)dst = *(float4*)&o[0];
  *(float4*)(dst + 8) = *(float4*)&o[8];
}

// ---------------------------------------------------------------------------
// FUSED q-GEMM + column softmax over d. 2-phase prefetch double-buffer.
// Keeps split-A (P precision is systematic). 48KB LDS / 3 blocks/CU.
// ---------------------------------------------------------------------------
__global__ __launch_bounds__(256) void q_gemm_softmax(const _Float16* __restrict__ Ahp,
                                                      const _Float16* __restrict__ Alp,
                                                      const _Float16* __restrict__ Bt,
                                                      _Float16* __restrict__ PT) {
  union alignas(16) QU {
    _Float16 st[2][3][128 * 32];  // [buf][Ah,Al,Bt] 48 KB dbuf staging
    _Float16 pt[128][128];        // 32 KB, epilogue P-tile (XOR-swizzled cols)
  };
  __shared__ QU u;
  const int tid = threadIdx.x;
  const int n0 = blockIdx.x * 128, m0 = blockIdx.y * 128;
  const int bz = blockIdx.z;
  const _Float16* Bp = Bt + (long)bz * NPIX * 256;
  const int wv = tid >> 6, l = tid & 63;
  const int r16 = l & 15, q = l >> 4;
  const int mb = (wv >> 1) * 64, nb = (wv & 1) * 64;
  const int r1 = tid >> 2;
  const int o1 = ((tid & 3) * 8) ^ (((r1 >> 1) & 3) * 8);
  const int r2 = r1 + 64;
  const int ldsc1 = (wv * 64) * 8;
  const int ldsc2 = (256 + wv * 64) * 8;
  const int q8 = (q * 8) ^ (((r16 >> 1) & 3) * 8);

  auto STAGE = [&](int buf, int kt) {
    const int k0 = kt * 32;
    async16(&u.st[buf][0][ldsc1], &Ahp[(long)(m0 + r1) * 256 + k0 + o1]);
    async16(&u.st[buf][0][ldsc2], &Ahp[(long)(m0 + r2) * 256 + k0 + o1]);
    async16(&u.st[buf][1][ldsc1], &Alp[(long)(m0 + r1) * 256 + k0 + o1]);
    async16(&u.st[buf][1][ldsc2], &Alp[(long)(m0 + r2) * 256 + k0 + o1]);
    async16(&u.st[buf][2][ldsc1], &Bp[(long)(n0 + r1) * 256 + k0 + o1]);
    async16(&u.st[buf][2][ldsc2], &Bp[(long)(n0 + r2) * 256 + k0 + o1]);
  };

  floatx4 acc[4][4];
#pragma unroll
  for (int i = 0; i < 4; i++)
#pragma unroll
    for (int j = 0; j < 4; j++) acc[i][j] = (floatx4){0.f, 0.f, 0.f, 0.f};

  STAGE(0, 0);
  __syncthreads();
  int cur = 0;
  for (int kt = 0; kt < 8; kt++) {
    if (kt < 7) STAGE(cur ^ 1, kt + 1);
    half8 fa[4], flo[4], fb[4];
#pragma unroll
    for (int i = 0; i < 4; i++) {
      fa[i] = *(const half8*)&u.st[cur][0][(mb + i * 16 + r16) * 32 + q8];
      flo[i] = *(const half8*)&u.st[cur][1][(mb + i * 16 + r16) * 32 + q8];
      fb[i] = *(const half8*)&u.st[cur][2][(nb + i * 16 + r16) * 32 + q8];
    }
#pragma unroll
    for (int i = 0; i < 4; i++)
#pragma unroll
      for (int j = 0; j < 4; j++) {
        acc[i][j] = __builtin_amdgcn_mfma_f32_16x16x32_f16(fa[i], fb[j], acc[i][j], 0, 0, 0);
        acc[i][j] = __builtin_amdgcn_mfma_f32_16x16x32_f16(flo[i], fb[j], acc[i][j], 0, 0, 0);
      }
    __syncthreads();
    cur ^= 1;
  }

  // ---- epilogue: per-column softmax over d (wave holds one head's 64 rows) ----
#pragma unroll
  for (int j = 0; j < 4; j++) {
    float s = 0.f;
#pragma unroll
    for (int i = 0; i < 4; i++)
#pragma unroll
      for (int t = 0; t < 4; t++) {
        float e = __expf(acc[i][j][t]);
        acc[i][j][t] = e;
        s += e;
      }
    s += __shfl_xor(s, 16, 64);
    s += __shfl_xor(s, 32, 64);
    const float rinv = 1.0f / s;
    const int nl = nb + j * 16 + r16;
    const int swz = (nl & 7) * 8;  // bank-spread: (q,nl&7) -> 32 distinct banks
#pragma unroll
    for (int i = 0; i < 4; i++) {
      half4 h4;
#pragma unroll
      for (int t = 0; t < 4; t++) h4[t] = (_Float16)(acc[i][j][t] * rinv);
      *(half4*)&u.pt[nl][(mb + i * 16 + q * 4) ^ swz] = h4;
    }
  }
  __syncthreads();
  // ---- dump P-tile: rows contiguous (PT row stride = 128 c), 1KB/wave-instr ----
  const int rbase = tid >> 4, c16 = tid & 15;
  _Float16* dst = PT + ((long)(bz * 2 + (m0 >> 7)) * NPIX + n0) * 128;
#pragma unroll
  for (int k = 0; k < 8; k++) {
    const int row = rbase + k * 16;
    const int chunk = c16 ^ (row & 7);
    float4 v = *(const float4*)&u.pt[row][chunk * 8];
    *(float4*)&dst[(long)row * 128 + c16 * 8] = v;
  }
}

// ---------------------------------------------------------------------------
// FUSED k/v GEMM + exp(k)@v^T context partials. SINGLE-precision A (no split):
// k,v are re-quantized to fp16 in the ev tile anyway, and per-n rounding
// washes by 1/sqrt(4096) in the Sum_n with Z from the same rounded values.
// Halves MFMA, staging 6->4 async16/kt, LDS 48->34.8KB -> 4 blocks/CU
// (grid 1024 = exactly 4/CU). CPB=2, c2 accumulates across chunks.
// ---------------------------------------------------------------------------
#define CPB 2
__global__ __launch_bounds__(256) void kv_ctx_gemm(const _Float16* __restrict__ Ahp,
                                                   const _Float16* __restrict__ Bt,
                                                   float* __restrict__ pbuf,
                                                   float* __restrict__ rsbuf) {
  union alignas(16) KVU {
    _Float16 st[2][2][128 * 32];  // [buf][A,B] 32 KB dbuf staging
    _Float16 ev[128][136];        // 34.8 KB epilogue: rows 0..63 exp(k), 64..127 v
  };
  __shared__ KVU u;
  const int tid = threadIdx.x;
  const int cg = blockIdx.x;     // 0..15 chunk-group (2 chunks of 128 each)
  const int hi = blockIdx.y;     // head 0..3
  const int b = blockIdx.z;
  const _Float16* Bp = Bt + (long)b * NPIX * 256;
  const int wv = tid >> 6, l = tid & 63;
  const int r16 = l & 15, q = l >> 4;
  const int mb = (wv >> 1) * 64, nb = (wv & 1) * 64;
  const int r1 = tid >> 2;
  const int o1 = ((tid & 3) * 8) ^ (((r1 >> 1) & 3) * 8);
  const int ldsc1 = (wv * 64) * 8;
  const int ldsc2 = (256 + wv * 64) * 8;
  const int q8 = (q * 8) ^ (((r16 >> 1) & 3) * 8);
  // A rows: local 0..63 = k[head hi], 64..127 = v[head hi]
  const long gAk = (long)(256 + hi * 64 + r1) * 256;
  const long gAv = (long)(512 + hi * 64 + r1) * 256;

  auto STAGE = [&](int buf, int kt, int n0) {
    const int k0 = kt * 32;
    async16(&u.st[buf][0][ldsc1], &Ahp[gAk + k0 + o1]);
    async16(&u.st[buf][0][ldsc2], &Ahp[gAv + k0 + o1]);
    async16(&u.st[buf][1][ldsc1], &Bp[(long)(n0 + r1) * 256 + k0 + o1]);
    async16(&u.st[buf][1][ldsc2], &Bp[(long)(n0 + 64 + r1) * 256 + k0 + o1]);
  };

  floatx4 c2[4];
#pragma unroll
  for (int j = 0; j < 4; j++) c2[j] = (floatx4){0.f, 0.f, 0.f, 0.f};
  float rs = 0.f;

  for (int cs = 0; cs < CPB; cs++) {
    const int n0 = (cg * CPB + cs) * 128;
    floatx4 acc[4][4];
#pragma unroll
    for (int i = 0; i < 4; i++)
#pragma unroll
      for (int j = 0; j < 4; j++) acc[i][j] = (floatx4){0.f, 0.f, 0.f, 0.f};

    STAGE(0, 0, n0);
    __syncthreads();
    int cur = 0;
    for (int kt = 0; kt < 8; kt++) {
      if (kt < 7) STAGE(cur ^ 1, kt + 1, n0);
      half8 fa[4], fb[4];
#pragma unroll
      for (int i = 0; i < 4; i++) {
        fa[i] = *(const half8*)&u.st[cur][0][(mb + i * 16 + r16) * 32 + q8];
        fb[i] = *(const half8*)&u.st[cur][1][(nb + i * 16 + r16) * 32 + q8];
      }
#pragma unroll
      for (int i = 0; i < 4; i++)
#pragma unroll
        for (int j = 0; j < 4; j++) {
          acc[i][j] = __builtin_amdgcn_mfma_f32_16x16x32_f16(fa[i], fb[j], acc[i][j], 0, 0, 0);
        }
      __syncthreads();
      cur ^= 1;
    }

    // ---- epilogue: acc -> exp(k)/v fp16 tile in LDS (stride 136) ----
    const bool is_k = (mb == 0);
#pragma unroll
    for (int i = 0; i < 4; i++) {
      const int row = mb + i * 16 + q * 4;
#pragma unroll
      for (int j = 0; j < 4; j++) {
        const int col = nb + j * 16 + r16;
#pragma unroll
        for (int t = 0; t < 4; t++) {
          const float vv0 = acc[i][j][t];
          u.ev[row + t][col] = (_Float16)(is_k ? __expf(vv0) : vv0);
        }
      }
    }
    __syncthreads();

    // ---- context partial: c2[d][e] += sum_n exp(k[d][n]) v[e][n], K=128 ----
#pragma unroll
    for (int ks = 0; ks < 4; ks++) {
      half8 a = *(const half8*)&u.ev[wv * 16 + r16][ks * 32 + q * 8];
#pragma unroll
      for (int ii = 0; ii < 8; ii++) rs += (float)a[ii];
#pragma unroll
      for (int j = 0; j < 4; j++) {
        half8 bv = *(const half8*)&u.ev[64 + j * 16 + r16][ks * 32 + q * 8];
        c2[j] = __builtin_amdgcn_mfma_f32_16x16x32_f16(a, bv, c2[j], 0, 0, 0);
      }
    }
    __syncthreads();  // ev reads done before next chunk's STAGE overwrites
  }

  rs += __shfl_xor(rs, 16, 64);
  rs += __shfl_xor(rs, 32, 64);
  const int bh = b * 4 + hi;
  float* pp = pbuf + ((long)bh * 16 + cg) * 4096;
#pragma unroll
  for (int j = 0; j < 4; j++)
#pragma unroll
    for (int reg = 0; reg < 4; reg++)
      pp[(wv * 16 + q * 4 + reg) * 64 + j * 16 + r16] = c2[j][reg];
  if (l < 16) rsbuf[((long)bh * 16 + cg) * 64 + wv * 16 + r16] = rs;
}

// ---------------------------------------------------------------------------
// FUSED reduce_ctx + zinv + mctx (was 3 dispatches):
//   ctx[d][e] = sum_16 pbuf partials (summed in-block, pbuf is L3-resident)
//   kinvz[d]  = 1 / sum_16 rsbuf
//   M_b[c][h*64+d] = SCALE * kinvz[d] * sum_e w_out[c][h*64+e] * ctx[d][e]
// ---------------------------------------------------------------------------
__global__ __launch_bounds__(256) void mctx_fused(const float* __restrict__ w_out,
                                                  const float* __restrict__ pbuf,
                                                  const float* __restrict__ rsbuf,
                                                  _Float16* __restrict__ Mhi,
                                                  _Float16* __restrict__ Mlo) {
  __shared__ float sctxT[64][65];  // [e][d], +1 pad
  __shared__ float sinv[64];
  const int cq = blockIdx.x, h = blockIdx.y, b = blockIdx.z;
  const int bh = b * 4 + h;
  const float* pp = pbuf + (long)bh * 16 * 4096;  // 16 partials of [d][e]
  const int tid = threadIdx.x;
  {
    const int d = tid >> 2, e0 = (tid & 3) * 16;
    float s0[16];
#pragma unroll
    for (int i = 0; i < 16; i++) s0[i] = 0.f;
    for (int c = 0; c < 16; c++) {
#pragma unroll
      for (int k = 0; k < 4; k++) {
        float4 v = *(const float4*)&pp[(long)c * 4096 + d * 64 + e0 + k * 4];
        s0[k * 4 + 0] += v.x;
        s0[k * 4 + 1] += v.y;
        s0[k * 4 + 2] += v.z;
        s0[k * 4 + 3] += v.w;
      }
    }
#pragma unroll
    for (int i = 0; i < 16; i++) sctxT[e0 + i][d] = s0[i];
  }
  if (tid < 64) {
    const float* rp = rsbuf + (long)bh * 16 * 64 + tid;
    float z = 0.f;
#pragma unroll
    for (int c = 0; c < 16; c++) z += rp[c * 64];
    sinv[tid] = 1.0f / z;
  }
  __syncthreads();
  const int c = cq * 64 + (tid >> 2);
  const int d0 = (tid & 3) * 16;
  const float* wp = w_out + (long)c * 256 + h * 64;
  float acc[16];
#pragma unroll
  for (int i = 0; i < 16; i++) acc[i] = 0.f;
#pragma unroll
  for (int e4 = 0; e4 < 16; e4++) {
    float4 wv = *(const float4*)&wp[e4 * 4];
#pragma unroll
    for (int u2 = 0; u2 < 4; u2++) {
      const float we = ((const float*)&wv)[u2];
      const int e = e4 * 4 + u2;
#pragma unroll
      for (int dd = 0; dd < 16; dd++) acc[dd] = fmaf(we, sctxT[e][d0 + dd], acc[dd]);
    }
  }
  alignas(16) _Float16 hi16[16], lo16[16];
#pragma unroll
  for (int k4 = 0; k4 < 4; k4++) {
    float4 zv = *(const float4*)&sinv[d0 + k4 * 4];
#pragma unroll
    for (int u2 = 0; u2 < 4; u2++) {
      const int dd = k4 * 4 + u2;
      float v = acc[dd] * (SCALE * ((const float*)&zv)[u2]);
      _Float16 hh = (_Float16)v;
      hi16[dd] = hh;
      lo16[dd] = (_Float16)(v - (float)hh);
    }
  }
  _Float16* mh = Mhi + ((long)b * 256 + c) * 256 + h * 64 + d0;
  _Float16* ml = Mlo + ((long)b * 256 + c) * 256 + h * 64 + d0;
#pragma unroll
  for (int k = 0; k < 2; k++) {
    *(float4*)&mh[k * 8] = *(float4*)&hi16[k * 8];
    *(float4*)&ml[k * 8] = *(float4*)&lo16[k * 8];
  }
}

// ---------------------------------------------------------------------------
// final GEMM: out[b][256][4096] = (Mhi+Mlo)[b] @ PT[b]^T + b_out
// B layout: PT[b][s][4096][128], s = K-half (kt>>2). 2-phase prefetch.
// ---------------------------------------------------------------------------
__global__ __launch_bounds__(256) void out_gemm(const _Float16* __restrict__ Mhi,
                                                const _Float16* __restrict__ Mlo,
                                                const _Float16* __restrict__ PT,
                                                float* __restrict__ C,
                                                const float* __restrict__ bias) {
  __shared__ _Float16 st[2][3][128 * 32];  // 48 KB dbuf staging
  const int tid = threadIdx.x;
  const int n0 = blockIdx.x * 128, m0 = blockIdx.y * 128;
  const int b = blockIdx.z;
  const _Float16* Ah = Mhi + (long)b * 65536;
  const _Float16* Al = Mlo + (long)b * 65536;
  float* Cp = C + (long)b * 256 * NPIX;
  const int wv = tid >> 6, l = tid & 63;
  const int r16 = l & 15, q = l >> 4;
  const int mb = (wv >> 1) * 64, nb = (wv & 1) * 64;
  const int r1 = tid >> 2;
  const int o1 = ((tid & 3) * 8) ^ (((r1 >> 1) & 3) * 8);
  const int r2 = r1 + 64;
  const int ldsc1 = (wv * 64) * 8;
  const int ldsc2 = (256 + wv * 64) * 8;
  const int q8 = (q * 8) ^ (((r16 >> 1) & 3) * 8);

  auto STAGE = [&](int buf, int kt) {
    const int k0 = kt * 32;
    async16(&st[buf][0][ldsc1], &Ah[(long)(m0 + r1) * 256 + k0 + o1]);
    async16(&st[buf][0][ldsc2], &Ah[(long)(m0 + r2) * 256 + k0 + o1]);
    async16(&st[buf][1][ldsc1], &Al[(long)(m0 + r1) * 256 + k0 + o1]);
    async16(&st[buf][1][ldsc2], &Al[(long)(m0 + r2) * 256 + k0 + o1]);
    const _Float16* Bk = PT + ((long)(b * 2 + (kt >> 2)) * NPIX + n0) * 128;
    async16(&st[buf][2][ldsc1], &Bk[(long)r1 * 128 + (kt & 3) * 32 + o1]);
    async16(&st[buf][2][ldsc2], &Bk[(long)(r1 + 64) * 128 + (kt & 3) * 32 + o1]);
  };

  floatx4 acc[4][4];
#pragma unroll
  for (int i = 0; i < 4; i++)
#pragma unroll
    for (int j = 0; j < 4; j++) acc[i][j] = (floatx4){0.f, 0.f, 0.f, 0.f};

  STAGE(0, 0);
  __syncthreads();
  int cur = 0;
  for (int kt = 0; kt < 8; kt++) {
    if (kt < 7) STAGE(cur ^ 1, kt + 1);
    half8 fa[4], flo[4], fb[4];
#pragma unroll
    for (int i = 0; i < 4; i++) {
      fa[i] = *(const half8*)&st[cur][0][(mb + i * 16 + r16) * 32 + q8];
      flo[i] = *(const half8*)&st[cur][1][(mb + i * 16 + r16) * 32 + q8];
      fb[i] = *(const half8*)&st[cur][2][(nb + i * 16 + r16) * 32 + q8];
    }
#pragma unroll
    for (int i = 0; i < 4; i++)
#pragma unroll
      for (int j = 0; j < 4; j++) {
        acc[i][j] = __builtin_amdgcn_mfma_f32_16x16x32_f16(fa[i], fb[j], acc[i][j], 0, 0, 0);
        acc[i][j] = __builtin_amdgcn_mfma_f32_16x16x32_f16(flo[i], fb[j], acc[i][j], 0, 0, 0);
      }
    __syncthreads();
    cur ^= 1;
  }
#pragma unroll
  for (int i = 0; i < 4; i++) {
    const int mrow = m0 + mb + i * 16 + q * 4;
#pragma unroll
    for (int t = 0; t < 4; t++) {
      float bz = bias[mrow + t];
#pragma unroll
      for (int j = 0; j < 4; j++) {
        Cp[(long)(mrow + t) * NPIX + n0 + nb + j * 16 + r16] = acc[i][j][t] + bz;
      }
    }
  }
}

extern "C" void kernel_launch(void* const* d_in, const int* in_sizes, int n_in,
                              void* d_out, int out_size, void* d_ws, size_t ws_size,
                              hipStream_t stream) {
  const float* x = (const float*)d_in[0];      // [16][256][4096]
  const float* w_qkv = (const float*)d_in[1];  // [768][256]
  const float* w_out = (const float*)d_in[2];  // [256][256]
  const float* b_out = (const float*)d_in[3];  // [256]
  float* out = (float*)d_out;                  // [16][256][4096]

  // d_ws layout:
  _Float16* PT = (_Float16*)d_ws;                           // [16][2][4096][128] = 32 MB
  float* rsbuf = (float*)(PT + (long)16 * 2 * NPIX * 128);  // 64bh*16p*64 = 256 KB
  _Float16* wq_hi = (_Float16*)(rsbuf + 64 * 16 * 64);
  _Float16* wq_lo = wq_hi + 768 * 256;
  _Float16* Mhi = wq_lo + 768 * 256;                        // 16*256*256 fp16 = 2 MB
  _Float16* Mlo = Mhi + 16 * 256 * 256;                     // 2 MB
  // d_out scratch (dead until out_gemm writes it):
  _Float16* xt = (_Float16*)d_out;                          // [0..32MB)
  float* pbuf = (float*)d_out + (1 << 23);                  // [32MB..48MB): 64bh*16p*4096

  split16_kernel<<<768, 256, 0, stream>>>(w_qkv, wq_hi, wq_lo, 768 * 256);
  transpose16_kernel<<<dim3(64, 4, 16), 256, 0, stream>>>(x, xt);
  // fused k/v GEMM (single-fp16 A) + exp(k)@v^T context partials
  kv_ctx_gemm<<<dim3(16, 4, 16), 256, 0, stream>>>(wq_hi, xt, pbuf, rsbuf);
  // fused partial-reduce + 1/Z + M_b = w_out @ ctx^T * diag(SCALE*invZ)
  mctx_fused<<<dim3(4, 4, 16), 256, 0, stream>>>(w_out, pbuf, rsbuf, Mhi, Mlo);
  // fused q GEMM + softmax -> P fp16 (q fp32 never touches HBM)
  q_gemm_softmax<<<dim3(32, 2, 16), 256, 0, stream>>>(wq_hi, wq_lo, xt, PT);
  // final = M_b @ P_b + b_out
  out_gemm<<<dim3(32, 2, 16), 256, 0, stream>>>(Mhi, Mlo, PT, out, b_out);
}